// Round 6
// baseline (196.504 us; speedup 1.0000x reference)
//
#include <hip/hip_runtime.h>

#define NB 8
#define NN 4096
#define NS 1024
#define NC 64
#define OUT_PTS_OFF (NB*NS*3)
#define CAP 512
#define RB 0.2f
#define QPB 8

typedef __attribute__((ext_vector_type(8))) short bf16x8;
typedef __attribute__((ext_vector_type(4))) float f32x4;

static __device__ __forceinline__ short f2bf(float f){
  unsigned u = __float_as_uint(f);
  unsigned r = (u + 0x7FFFu + ((u>>16)&1u)) >> 16;
  return (short)r;
}
static __device__ __forceinline__ float bf2f(short s){
  return __uint_as_float(((unsigned)(unsigned short)s) << 16);
}
// packed f32->bf16 RTNE: low short = cvt(a), high short = cvt(b)
static __device__ __forceinline__ unsigned cvtpk(float a, float b){
  unsigned r;
  asm("v_cvt_pk_bf16_f32 %0, %1, %2" : "=v"(r) : "v"(a), "v"(b));
  return r;
}

// ws layout:
//   int   gsidx[8192][64]            @ byte 0        (2 MB)
//   short px1  [32768][64]           @ byte 2097152  (4 MB)
//   short wf   [47104]               @ byte 6291456  (94 KB)
//     wf0 [3][4][64][8] @0 ; wf1 [2][8][64][8] @6144 ; wf2 [4][16][64][8] @14336
#define WS_PX1_SH   1048576
#define WS_WF_SH    3145728

__global__ __launch_bounds__(256) void prep_weights(
    const float* __restrict__ w0, const float* __restrict__ w1,
    const float* __restrict__ w2, short* __restrict__ ws)
{
  int e = blockIdx.x*256 + threadIdx.x;
  if (e >= 47104) return;
  float v = 0.f;
  if (e < 6144) {
    int j=e&7, l=(e>>3)&63, nt=(e>>9)&3, kt=e>>11;
    int k = kt*32 + ((l>>4)<<3) + j, n = nt*16 + (l&15);
    if (k < 64) v = w0[(3+k)*64 + n];
    else if (k < 67) v = w0[(k-64)*64 + n];
  } else if (e < 14336) {
    int e2=e-6144;
    int j=e2&7, l=(e2>>3)&63, nt=(e2>>9)&7, kt=e2>>12;
    int k = kt*32 + ((l>>4)<<3) + j, n = nt*16 + (l&15);
    v = w1[k*128 + n];
  } else {
    int e3=e-14336;
    int j=e3&7, l=(e3>>3)&63, nt=(e3>>9)&15, kt=e3>>13;
    int p = kt*32 + ((l>>4)<<3) + j;      // physical k slot (h2 storage order)
    int k = ((p&7)<<4) + (p>>3);          // logical w2 row: h2 col p holds ch (p&7)*16+(p>>3)
    int n = nt*16 + (l&15);
    v = w2[k*256 + n];
  }
  ws[e] = f2bf(v);
}

// ---- PX1[b,n,f] = ([points, xyz] @ w0_perm)[b,n,f]   (bf16, NO relu) ----
__global__ __launch_bounds__(256) void px1_kernel(
    const float* __restrict__ xyz, const float* __restrict__ points,
    const short* __restrict__ wsb, short* __restrict__ px1)
{
  const int tid = threadIdx.x;
  const int w = tid>>6, l = tid&63, lr = l&15, grp = l>>4;
  const int rowbase = blockIdx.x*64 + w*16;
  const int row = rowbase + lr;
  const float* prow = points + (size_t)row*NC;
  const float* xr   = xyz + (size_t)row*3;

  bf16x8 a0, a1, a2;
  {
    float4 u0 = *(const float4*)(prow + grp*8);
    float4 u1 = *(const float4*)(prow + grp*8 + 4);
    float4 u2 = *(const float4*)(prow + 32 + grp*8);
    float4 u3 = *(const float4*)(prow + 32 + grp*8 + 4);
    a0 = (bf16x8){f2bf(u0.x),f2bf(u0.y),f2bf(u0.z),f2bf(u0.w),f2bf(u1.x),f2bf(u1.y),f2bf(u1.z),f2bf(u1.w)};
    a1 = (bf16x8){f2bf(u2.x),f2bf(u2.y),f2bf(u2.z),f2bf(u2.w),f2bf(u3.x),f2bf(u3.y),f2bf(u3.z),f2bf(u3.w)};
    short e0=0,e1=0,e2v=0;
    if (grp==0) { e0=f2bf(xr[0]); e1=f2bf(xr[1]); e2v=f2bf(xr[2]); }
    a2 = (bf16x8){e0,e1,e2v,0,0,0,0,0};
  }
  f32x4 zero4 = {0.f,0.f,0.f,0.f};
  #pragma unroll
  for (int nt=0; nt<4; ++nt) {
    f32x4 acc = zero4;
    bf16x8 b0 = *(const bf16x8*)(wsb + (((0*4+nt)*64 + l)<<3));
    bf16x8 b1 = *(const bf16x8*)(wsb + (((1*4+nt)*64 + l)<<3));
    bf16x8 b2 = *(const bf16x8*)(wsb + (((2*4+nt)*64 + l)<<3));
    acc = __builtin_amdgcn_mfma_f32_16x16x32_bf16(a0, b0, acc, 0,0,0);
    acc = __builtin_amdgcn_mfma_f32_16x16x32_bf16(a1, b1, acc, 0,0,0);
    acc = __builtin_amdgcn_mfma_f32_16x16x32_bf16(a2, b2, acc, 0,0,0);
    #pragma unroll
    for (int i=0;i<4;++i)
      px1[(size_t)(rowbase + grp*4 + i)*64 + nt*16 + lr] = f2bf(acc[i]);
  }
}

// ---- selection: 2 queries/block, points held in registers across both ----
__global__ __launch_bounds__(256) void select_kernel(
    const float* __restrict__ xyz, const int* __restrict__ fps_inds,
    int* __restrict__ gsidx, float* __restrict__ out)
{
  __shared__ unsigned int cand_d[CAP];
  __shared__ int cand_i[CAP];
  __shared__ int scnt[256];
  __shared__ int chunkbase[64];
  __shared__ int tmp64[64];
  __shared__ int sc0;

  const int q0 = blockIdx.x*2;          // even; q0 and q0+1 share batch b
  const int b = q0 >> 10, tid = threadIdx.x;
  const float* xb = xyz + (size_t)b*NN*3;

  // load this thread's 16 points once (48 VGPR), reuse for both queries
  float px[16], py[16], pz[16];
  {
    const float4* xv = (const float4*)(xb + tid*48);
    #pragma unroll
    for (int g=0; g<4; ++g) {
      float4 v0 = xv[g*3], v1 = xv[g*3+1], v2 = xv[g*3+2];
      px[g*4+0]=v0.x; px[g*4+1]=v0.w; px[g*4+2]=v1.z; px[g*4+3]=v2.y;
      py[g*4+0]=v0.y; py[g*4+1]=v1.x; py[g*4+2]=v1.w; py[g*4+3]=v2.z;
      pz[g*4+0]=v0.z; pz[g*4+1]=v1.y; pz[g*4+2]=v2.x; pz[g*4+3]=v2.w;
    }
  }

  for (int qq = 0; qq < 2; ++qq) {
    if (qq) __syncthreads();            // protect LDS reuse
    const int q = q0 + qq;
    const int fps = fps_inds[q];
    const float qx = xb[fps*3+0], qy = xb[fps*3+1], qz = xb[fps*3+2];
    if (tid < 3) out[q*3+tid] = xb[fps*3+tid];

    unsigned int dbits[16]; unsigned int msk=0; int c=0;
    #pragma unroll
    for (int r=0; r<16; ++r) {
      float dx=__fsub_rn(qx,px[r]), dy=__fsub_rn(qy,py[r]), dz=__fsub_rn(qz,pz[r]);
      float d2=__fadd_rn(__fadd_rn(__fmul_rn(dx,dx),__fmul_rn(dy,dy)),__fmul_rn(dz,dz));
      float d = __fsqrt_rn(d2);
      dbits[r] = __float_as_uint(d);
      if (d < RB) { msk |= 1u<<r; c++; }
    }
    scnt[tid] = c; __syncthreads();
    if (tid < 64) {
      int s = scnt[tid*4]+scnt[tid*4+1]+scnt[tid*4+2]+scnt[tid*4+3];
      int incl = s;
      #pragma unroll
      for (int off=1; off<64; off<<=1) {
        int vv = __shfl_up(incl, off, 64);
        if (tid >= off) incl += vv;
      }
      chunkbase[tid] = incl - s;
      if (tid == 63) sc0 = incl;
    }
    __syncthreads();
    int cnt = sc0; if (cnt > CAP) cnt = CAP;
    {
      int base = chunkbase[tid>>2];
      for (int u = (tid & ~3); u < tid; ++u) base += scnt[u];
      #pragma unroll
      for (int r=0; r<16; ++r) {
        if (msk & (1u<<r)) {
          if (base < CAP) { cand_d[base] = dbits[r]; cand_i[base] = tid*16+r; }
          base++;
        }
      }
    }
    __syncthreads();

    if (cnt > 64) {
      for (int j=tid; j<cnt; j+=256) {
        unsigned dj = cand_d[j]; int rk=0;
        for (int i=0;i<cnt;++i) { unsigned di=cand_d[i]; rk += (int)((di<dj) | ((di==dj) & (i<j))); }
        if (rk < 64) tmp64[rk] = cand_i[j];
      }
      __syncthreads();
      if (tid < 64) {
        int v = tmp64[tid]; int p=0;
        for (int u=0;u<64;++u) p += (tmp64[u] < v);
        gsidx[q*64 + p] = v;
      }
    } else {
      if (tid < 64) gsidx[q*64 + tid] = cand_i[tid < cnt ? tid : 0];
    }
  }
}

// ---- MLP: persistent QPB queries/block; wf2 in regs, wf1 in LDS ----
// h2 storage: phys col p = lr*8 + nt holds logical channel nt*16+lr (wf2 k-relabeled
// to match); byte col XOR-swizzled by ((row&7)<<4) on both write & read sides.
__global__ __launch_bounds__(256,4) void mlp_kernel(
    const float* __restrict__ xyz, const int* __restrict__ fps_inds,
    const float* __restrict__ w0, const short* __restrict__ wsb,
    const short* __restrict__ px1, const int* __restrict__ gsidx,
    float* __restrict__ out)
{
  __shared__ __align__(16) short w1s[16*64*8];   // 16384 B, loaded once
  __shared__ __align__(16) short h2[64][136];    // 17408 B, single-buffered
  __shared__ float q1s[QPB][64];
  __shared__ int sidx[QPB][64];

  const int tid = threadIdx.x;
  const int w = tid>>6, l = tid&63, lr = l&15, grp = l>>4;
  const int q0 = blockIdx.x*QPB;
  const int b = q0 >> 10;
  const float* xb = xyz + (size_t)b*NN*3;

  // loop-invariant: layer-3 B frags for this wave's 4 ntiles (64 VGPR)
  bf16x8 b3[4][4];
  #pragma unroll
  for (int kt=0; kt<4; ++kt)
    #pragma unroll
    for (int j=0; j<4; ++j)
      b3[kt][j] = *(const bf16x8*)(wsb + 14336 + (((kt*16 + w*4 + j)*64 + l)<<3));

  // prologue: wf1 -> LDS (16 KB), sidx + q1s for all QPB queries
  #pragma unroll
  for (int e = 0; e < 4; ++e) {
    int s = tid + e*256;
    *(bf16x8*)&w1s[s*8] = *(const bf16x8*)(wsb + 6144 + s*8);
  }
  for (int e = tid; e < QPB*64; e += 256) {
    int qq = e>>6, t = e&63;
    int fp = fps_inds[q0+qq];
    sidx[qq][t] = gsidx[(q0+qq)*64 + t];
    q1s[qq][t] = xb[fp*3]*w0[t] + xb[fp*3+1]*w0[64+t] + xb[fp*3+2]*w0[128+t];
  }
  if (tid < QPB*3) {
    int qq = tid/3, c = tid - qq*3;
    int fp = fps_inds[q0+qq];
    out[(q0+qq)*3 + c] = xb[fp*3+c];
  }
  __syncthreads();

  const short* px1b = px1 + (size_t)b*NN*64;
  const int myrow = w*16 + lr;

  bf16x8 v0, v1;
  {
    int idx = sidx[0][myrow];
    v0 = *(const bf16x8*)(px1b + idx*64 + grp*8);
    v1 = *(const bf16x8*)(px1b + idx*64 + 32 + grp*8);
  }

  f32x4 zero4 = {0.f,0.f,0.f,0.f};

  for (int qq = 0; qq < QPB; ++qq) {
    if (qq) __syncthreads();      // h2 reads (prev query) done before rewrite

    // h1 row: relu(PX1[idx] - Q1), packed via cvt_pk
    bf16x8 a20, a21;
    {
      union { unsigned u[4]; bf16x8 v; } ua, ub;
      #pragma unroll
      for (int jp=0; jp<4; ++jp) {
        float x0 = fmaxf(bf2f(v0[2*jp  ]) - q1s[qq][grp*8+2*jp  ], 0.f);
        float x1 = fmaxf(bf2f(v0[2*jp+1]) - q1s[qq][grp*8+2*jp+1], 0.f);
        ua.u[jp] = cvtpk(x0, x1);
        float y0 = fmaxf(bf2f(v1[2*jp  ]) - q1s[qq][32+grp*8+2*jp  ], 0.f);
        float y1 = fmaxf(bf2f(v1[2*jp+1]) - q1s[qq][32+grp*8+2*jp+1], 0.f);
        ub.u[jp] = cvtpk(y0, y1);
      }
      a20 = ua.v; a21 = ub.v;
    }
    if (qq+1 < QPB) {             // prefetch next query's px1 row
      int idx = sidx[qq+1][myrow];
      v0 = *(const bf16x8*)(px1b + idx*64 + grp*8);
      v1 = *(const bf16x8*)(px1b + idx*64 + 32 + grp*8);
    }

    // layer 2: nt in pairs; B from LDS; packed b32 stores into permuted h2
    #pragma unroll
    for (int ntp=0; ntp<4; ++ntp) {
      f32x4 accA = zero4, accB = zero4;
      bf16x8 bA0 = *(const bf16x8*)&w1s[((0*8 + 2*ntp  )*64 + l)*8];
      bf16x8 bA1 = *(const bf16x8*)&w1s[((1*8 + 2*ntp  )*64 + l)*8];
      bf16x8 bB0 = *(const bf16x8*)&w1s[((0*8 + 2*ntp+1)*64 + l)*8];
      bf16x8 bB1 = *(const bf16x8*)&w1s[((1*8 + 2*ntp+1)*64 + l)*8];
      accA = __builtin_amdgcn_mfma_f32_16x16x32_bf16(a20, bA0, accA, 0,0,0);
      accA = __builtin_amdgcn_mfma_f32_16x16x32_bf16(a21, bA1, accA, 0,0,0);
      accB = __builtin_amdgcn_mfma_f32_16x16x32_bf16(a20, bB0, accB, 0,0,0);
      accB = __builtin_amdgcn_mfma_f32_16x16x32_bf16(a21, bB1, accB, 0,0,0);
      #pragma unroll
      for (int i=0; i<4; ++i) {
        int row = w*16 + grp*4 + i;
        unsigned u = cvtpk(fmaxf(accA[i],0.f), fmaxf(accB[i],0.f));
        int colb = (lr*16 + ntp*4) ^ ((row&7)<<4);
        *(unsigned*)((char*)&h2[row][0] + colb) = u;
      }
    }
    __syncthreads();

    // layer 3: all 64 rows x wave's 4 ntiles; A from swizzled h2, B from regs
    f32x4 acc3[4][4];
    #pragma unroll
    for (int mt=0; mt<4; ++mt)
      #pragma unroll
      for (int j=0; j<4; ++j) acc3[mt][j] = zero4;
    #pragma unroll
    for (int kt=0; kt<4; ++kt)
      #pragma unroll
      for (int mt=0; mt<4; ++mt) {
        int row = mt*16 + lr;
        int colb = (kt*64 + grp*16) ^ ((row&7)<<4);
        bf16x8 a = *(const bf16x8*)((const char*)&h2[row][0] + colb);
        #pragma unroll
        for (int j=0; j<4; ++j)
          acc3[mt][j] = __builtin_amdgcn_mfma_f32_16x16x32_bf16(a, b3[kt][j], acc3[mt][j], 0,0,0);
      }
    #pragma unroll
    for (int j=0; j<4; ++j) {
      float m = 0.f;   // relu folded into maxpool
      #pragma unroll
      for (int mt=0; mt<4; ++mt) {
        f32x4 t = acc3[mt][j];
        m = fmaxf(m, fmaxf(fmaxf(t[0],t[1]), fmaxf(t[2],t[3])));
      }
      m = fmaxf(m, __shfl_xor(m, 16, 64));
      m = fmaxf(m, __shfl_xor(m, 32, 64));
      if (grp == 0) out[OUT_PTS_OFF + (q0+qq)*256 + (w*4+j)*16 + lr] = m;
    }
  }
}

extern "C" void kernel_launch(void* const* d_in, const int* in_sizes, int n_in,
                              void* d_out, int out_size, void* d_ws, size_t ws_size,
                              hipStream_t stream) {
  const float* xyz      = (const float*)d_in[0];
  const float* points   = (const float*)d_in[1];
  const int*   fps_inds = (const int*)d_in[2];
  const float* w0       = (const float*)d_in[3];
  const float* w1       = (const float*)d_in[4];
  const float* w2       = (const float*)d_in[5];
  float* out = (float*)d_out;

  int*   gsidx = (int*)d_ws;
  short* px1   = (short*)d_ws + WS_PX1_SH;
  short* wsb   = (short*)d_ws + WS_WF_SH;

  hipLaunchKernelGGL(prep_weights, dim3(184), dim3(256), 0, stream, w0, w1, w2, wsb);
  hipLaunchKernelGGL(px1_kernel,   dim3(512), dim3(256), 0, stream, xyz, points, wsb, px1);
  hipLaunchKernelGGL(select_kernel,dim3(NB*NS/2), dim3(256), 0, stream, xyz, fps_inds, gsidx, out);
  hipLaunchKernelGGL(mlp_kernel,   dim3(NB*NS/QPB), dim3(256), 0, stream,
                     xyz, fps_inds, w0, wsb, px1, gsidx, out);
}

// Round 7
// 124.542 us; speedup vs baseline: 1.5778x; 1.5778x over previous
//
#include <hip/hip_runtime.h>

#define NB 8
#define NN 4096
#define NS 1024
#define NC 64
#define OUT_PTS_OFF (NB*NS*3)
#define CAP 512
#define RB 0.2f
#define QPB 8

typedef __attribute__((ext_vector_type(8))) short bf16x8;
typedef __attribute__((ext_vector_type(4))) float f32x4;

static __device__ __forceinline__ short f2bf(float f){
  unsigned u = __float_as_uint(f);
  unsigned r = (u + 0x7FFFu + ((u>>16)&1u)) >> 16;
  return (short)r;
}
static __device__ __forceinline__ float bf2f(short s){
  return __uint_as_float(((unsigned)(unsigned short)s) << 16);
}
// packed f32->bf16 RTNE: low short = cvt(a), high short = cvt(b)
static __device__ __forceinline__ unsigned cvtpk(float a, float b){
  unsigned r;
  asm("v_cvt_pk_bf16_f32 %0, %1, %2" : "=v"(r) : "v"(a), "v"(b));
  return r;
}

// ws layout:
//   int   gsidx[8192][64]            @ byte 0        (2 MB)
//   short px1  [32768][64]           @ byte 2097152  (4 MB)
//   short wf   [47104]               @ byte 6291456  (94 KB)
//     wf0 [3][4][64][8] @0 ; wf1 [2][8][64][8] @6144 ; wf2 [4][16][64][8] @14336
#define WS_PX1_SH   1048576
#define WS_WF_SH    3145728

__global__ __launch_bounds__(256) void prep_weights(
    const float* __restrict__ w0, const float* __restrict__ w1,
    const float* __restrict__ w2, short* __restrict__ ws)
{
  int e = blockIdx.x*256 + threadIdx.x;
  if (e >= 47104) return;
  float v = 0.f;
  if (e < 6144) {
    int j=e&7, l=(e>>3)&63, nt=(e>>9)&3, kt=e>>11;
    int k = kt*32 + ((l>>4)<<3) + j, n = nt*16 + (l&15);
    if (k < 64) v = w0[(3+k)*64 + n];
    else if (k < 67) v = w0[(k-64)*64 + n];
  } else if (e < 14336) {
    int e2=e-6144;
    int j=e2&7, l=(e2>>3)&63, nt=(e2>>9)&7, kt=e2>>12;
    int k = kt*32 + ((l>>4)<<3) + j, n = nt*16 + (l&15);
    v = w1[k*128 + n];
  } else {
    int e3=e-14336;
    int j=e3&7, l=(e3>>3)&63, nt=(e3>>9)&15, kt=e3>>13;
    int p = kt*32 + ((l>>4)<<3) + j;      // physical k slot (h2 storage order)
    int k = ((p&7)<<4) + (p>>3);          // logical w2 row: h2 col p holds ch (p&7)*16+(p>>3)
    int n = nt*16 + (l&15);
    v = w2[k*256 + n];
  }
  ws[e] = f2bf(v);
}

// ---- PX1[b,n,f] = ([points, xyz] @ w0_perm)[b,n,f]   (bf16, NO relu) ----
__global__ __launch_bounds__(256) void px1_kernel(
    const float* __restrict__ xyz, const float* __restrict__ points,
    const short* __restrict__ wsb, short* __restrict__ px1)
{
  const int tid = threadIdx.x;
  const int w = tid>>6, l = tid&63, lr = l&15, grp = l>>4;
  const int rowbase = blockIdx.x*64 + w*16;
  const int row = rowbase + lr;
  const float* prow = points + (size_t)row*NC;
  const float* xr   = xyz + (size_t)row*3;

  bf16x8 a0, a1, a2;
  {
    float4 u0 = *(const float4*)(prow + grp*8);
    float4 u1 = *(const float4*)(prow + grp*8 + 4);
    float4 u2 = *(const float4*)(prow + 32 + grp*8);
    float4 u3 = *(const float4*)(prow + 32 + grp*8 + 4);
    a0 = (bf16x8){f2bf(u0.x),f2bf(u0.y),f2bf(u0.z),f2bf(u0.w),f2bf(u1.x),f2bf(u1.y),f2bf(u1.z),f2bf(u1.w)};
    a1 = (bf16x8){f2bf(u2.x),f2bf(u2.y),f2bf(u2.z),f2bf(u2.w),f2bf(u3.x),f2bf(u3.y),f2bf(u3.z),f2bf(u3.w)};
    short e0=0,e1=0,e2v=0;
    if (grp==0) { e0=f2bf(xr[0]); e1=f2bf(xr[1]); e2v=f2bf(xr[2]); }
    a2 = (bf16x8){e0,e1,e2v,0,0,0,0,0};
  }
  f32x4 zero4 = {0.f,0.f,0.f,0.f};
  #pragma unroll
  for (int nt=0; nt<4; ++nt) {
    f32x4 acc = zero4;
    bf16x8 b0 = *(const bf16x8*)(wsb + (((0*4+nt)*64 + l)<<3));
    bf16x8 b1 = *(const bf16x8*)(wsb + (((1*4+nt)*64 + l)<<3));
    bf16x8 b2 = *(const bf16x8*)(wsb + (((2*4+nt)*64 + l)<<3));
    acc = __builtin_amdgcn_mfma_f32_16x16x32_bf16(a0, b0, acc, 0,0,0);
    acc = __builtin_amdgcn_mfma_f32_16x16x32_bf16(a1, b1, acc, 0,0,0);
    acc = __builtin_amdgcn_mfma_f32_16x16x32_bf16(a2, b2, acc, 0,0,0);
    #pragma unroll
    for (int i=0;i<4;++i)
      px1[(size_t)(rowbase + grp*4 + i)*64 + nt*16 + lr] = f2bf(acc[i]);
  }
}

// ---- selection: 2 queries/block, points held in registers across both ----
__global__ __launch_bounds__(256) void select_kernel(
    const float* __restrict__ xyz, const int* __restrict__ fps_inds,
    int* __restrict__ gsidx, float* __restrict__ out)
{
  __shared__ unsigned int cand_d[CAP];
  __shared__ int cand_i[CAP];
  __shared__ int scnt[256];
  __shared__ int chunkbase[64];
  __shared__ int tmp64[64];
  __shared__ int sc0;

  const int q0 = blockIdx.x*2;          // even; q0 and q0+1 share batch b
  const int b = q0 >> 10, tid = threadIdx.x;
  const float* xb = xyz + (size_t)b*NN*3;

  // load this thread's 16 points once (48 VGPR), reuse for both queries
  float px[16], py[16], pz[16];
  {
    const float4* xv = (const float4*)(xb + tid*48);
    #pragma unroll
    for (int g=0; g<4; ++g) {
      float4 v0 = xv[g*3], v1 = xv[g*3+1], v2 = xv[g*3+2];
      px[g*4+0]=v0.x; px[g*4+1]=v0.w; px[g*4+2]=v1.z; px[g*4+3]=v2.y;
      py[g*4+0]=v0.y; py[g*4+1]=v1.x; py[g*4+2]=v1.w; py[g*4+3]=v2.z;
      pz[g*4+0]=v0.z; pz[g*4+1]=v1.y; pz[g*4+2]=v2.x; pz[g*4+3]=v2.w;
    }
  }

  for (int qq = 0; qq < 2; ++qq) {
    if (qq) __syncthreads();            // protect LDS reuse
    const int q = q0 + qq;
    const int fps = fps_inds[q];
    const float qx = xb[fps*3+0], qy = xb[fps*3+1], qz = xb[fps*3+2];
    if (tid < 3) out[q*3+tid] = xb[fps*3+tid];

    unsigned int dbits[16]; unsigned int msk=0; int c=0;
    #pragma unroll
    for (int r=0; r<16; ++r) {
      float dx=__fsub_rn(qx,px[r]), dy=__fsub_rn(qy,py[r]), dz=__fsub_rn(qz,pz[r]);
      float d2=__fadd_rn(__fadd_rn(__fmul_rn(dx,dx),__fmul_rn(dy,dy)),__fmul_rn(dz,dz));
      float d = __fsqrt_rn(d2);
      dbits[r] = __float_as_uint(d);
      if (d < RB) { msk |= 1u<<r; c++; }
    }
    scnt[tid] = c; __syncthreads();
    if (tid < 64) {
      int s = scnt[tid*4]+scnt[tid*4+1]+scnt[tid*4+2]+scnt[tid*4+3];
      int incl = s;
      #pragma unroll
      for (int off=1; off<64; off<<=1) {
        int vv = __shfl_up(incl, off, 64);
        if (tid >= off) incl += vv;
      }
      chunkbase[tid] = incl - s;
      if (tid == 63) sc0 = incl;
    }
    __syncthreads();
    int cnt = sc0; if (cnt > CAP) cnt = CAP;
    {
      int base = chunkbase[tid>>2];
      for (int u = (tid & ~3); u < tid; ++u) base += scnt[u];
      #pragma unroll
      for (int r=0; r<16; ++r) {
        if (msk & (1u<<r)) {
          if (base < CAP) { cand_d[base] = dbits[r]; cand_i[base] = tid*16+r; }
          base++;
        }
      }
    }
    __syncthreads();

    if (cnt > 64) {
      for (int j=tid; j<cnt; j+=256) {
        unsigned dj = cand_d[j]; int rk=0;
        for (int i=0;i<cnt;++i) { unsigned di=cand_d[i]; rk += (int)((di<dj) | ((di==dj) & (i<j))); }
        if (rk < 64) tmp64[rk] = cand_i[j];
      }
      __syncthreads();
      if (tid < 64) {
        int v = tmp64[tid]; int p=0;
        for (int u=0;u<64;++u) p += (tmp64[u] < v);
        gsidx[q*64 + p] = v;
      }
    } else {
      if (tid < 64) gsidx[q*64 + tid] = cand_i[tid < cnt ? tid : 0];
    }
  }
}

// ---- MLP: persistent QPB queries/block; wf2 in regs, wf1 in LDS ----
// h2 storage: phys col p = lr*8 + nt holds logical channel nt*16+lr (wf2 k-relabeled
// to match); byte col XOR-swizzled by ((row&7)<<4) on both write & read sides.
// launch_bounds (256,2): DO NOT raise the occupancy request — (256,4) capped the
// allocator below the ~128 VGPR this kernel needs and spilled b3 to scratch
// (R6: VGPR=64, FETCH 336MB, 139us).
__global__ __launch_bounds__(256,2) void mlp_kernel(
    const float* __restrict__ xyz, const int* __restrict__ fps_inds,
    const float* __restrict__ w0, const short* __restrict__ wsb,
    const short* __restrict__ px1, const int* __restrict__ gsidx,
    float* __restrict__ out)
{
  __shared__ __align__(16) short w1s[16*64*8];   // 16384 B, loaded once
  __shared__ __align__(16) short h2[64][136];    // 17408 B, single-buffered
  __shared__ float q1s[QPB][64];
  __shared__ int sidx[QPB][64];

  const int tid = threadIdx.x;
  const int w = tid>>6, l = tid&63, lr = l&15, grp = l>>4;
  const int q0 = blockIdx.x*QPB;
  const int b = q0 >> 10;
  const float* xb = xyz + (size_t)b*NN*3;

  // loop-invariant: layer-3 B frags for this wave's 4 ntiles (64 VGPR)
  bf16x8 b3[4][4];
  #pragma unroll
  for (int kt=0; kt<4; ++kt)
    #pragma unroll
    for (int j=0; j<4; ++j)
      b3[kt][j] = *(const bf16x8*)(wsb + 14336 + (((kt*16 + w*4 + j)*64 + l)<<3));

  // prologue: wf1 -> LDS (16 KB), sidx + q1s for all QPB queries
  #pragma unroll
  for (int e = 0; e < 4; ++e) {
    int s = tid + e*256;
    *(bf16x8*)&w1s[s*8] = *(const bf16x8*)(wsb + 6144 + s*8);
  }
  for (int e = tid; e < QPB*64; e += 256) {
    int qq = e>>6, t = e&63;
    int fp = fps_inds[q0+qq];
    sidx[qq][t] = gsidx[(q0+qq)*64 + t];
    q1s[qq][t] = xb[fp*3]*w0[t] + xb[fp*3+1]*w0[64+t] + xb[fp*3+2]*w0[128+t];
  }
  if (tid < QPB*3) {
    int qq = tid/3, c = tid - qq*3;
    int fp = fps_inds[q0+qq];
    out[(q0+qq)*3 + c] = xb[fp*3+c];
  }
  __syncthreads();

  const short* px1b = px1 + (size_t)b*NN*64;
  const int myrow = w*16 + lr;

  bf16x8 v0, v1;
  {
    int idx = sidx[0][myrow];
    v0 = *(const bf16x8*)(px1b + idx*64 + grp*8);
    v1 = *(const bf16x8*)(px1b + idx*64 + 32 + grp*8);
  }

  f32x4 zero4 = {0.f,0.f,0.f,0.f};

  for (int qq = 0; qq < QPB; ++qq) {
    if (qq) __syncthreads();      // h2 reads (prev query) done before rewrite

    // h1 row: relu(PX1[idx] - Q1), packed via cvt_pk
    bf16x8 a20, a21;
    {
      union { unsigned u[4]; bf16x8 v; } ua, ub;
      #pragma unroll
      for (int jp=0; jp<4; ++jp) {
        float x0 = fmaxf(bf2f(v0[2*jp  ]) - q1s[qq][grp*8+2*jp  ], 0.f);
        float x1 = fmaxf(bf2f(v0[2*jp+1]) - q1s[qq][grp*8+2*jp+1], 0.f);
        ua.u[jp] = cvtpk(x0, x1);
        float y0 = fmaxf(bf2f(v1[2*jp  ]) - q1s[qq][32+grp*8+2*jp  ], 0.f);
        float y1 = fmaxf(bf2f(v1[2*jp+1]) - q1s[qq][32+grp*8+2*jp+1], 0.f);
        ub.u[jp] = cvtpk(y0, y1);
      }
      a20 = ua.v; a21 = ub.v;
    }
    if (qq+1 < QPB) {             // prefetch next query's px1 row
      int idx = sidx[qq+1][myrow];
      v0 = *(const bf16x8*)(px1b + idx*64 + grp*8);
      v1 = *(const bf16x8*)(px1b + idx*64 + 32 + grp*8);
    }

    // layer 2: nt in pairs; B from LDS; packed b32 stores into permuted h2
    #pragma unroll
    for (int ntp=0; ntp<4; ++ntp) {
      f32x4 accA = zero4, accB = zero4;
      bf16x8 bA0 = *(const bf16x8*)&w1s[((0*8 + 2*ntp  )*64 + l)*8];
      bf16x8 bA1 = *(const bf16x8*)&w1s[((1*8 + 2*ntp  )*64 + l)*8];
      bf16x8 bB0 = *(const bf16x8*)&w1s[((0*8 + 2*ntp+1)*64 + l)*8];
      bf16x8 bB1 = *(const bf16x8*)&w1s[((1*8 + 2*ntp+1)*64 + l)*8];
      accA = __builtin_amdgcn_mfma_f32_16x16x32_bf16(a20, bA0, accA, 0,0,0);
      accA = __builtin_amdgcn_mfma_f32_16x16x32_bf16(a21, bA1, accA, 0,0,0);
      accB = __builtin_amdgcn_mfma_f32_16x16x32_bf16(a20, bB0, accB, 0,0,0);
      accB = __builtin_amdgcn_mfma_f32_16x16x32_bf16(a21, bB1, accB, 0,0,0);
      #pragma unroll
      for (int i=0; i<4; ++i) {
        int row = w*16 + grp*4 + i;
        unsigned u = cvtpk(fmaxf(accA[i],0.f), fmaxf(accB[i],0.f));
        int colb = (lr*16 + ntp*4) ^ ((row&7)<<4);
        *(unsigned*)((char*)&h2[row][0] + colb) = u;
      }
    }
    __syncthreads();

    // layer 3: all 64 rows x wave's 4 ntiles; A from swizzled h2, B from regs
    f32x4 acc3[4][4];
    #pragma unroll
    for (int mt=0; mt<4; ++mt)
      #pragma unroll
      for (int j=0; j<4; ++j) acc3[mt][j] = zero4;
    #pragma unroll
    for (int kt=0; kt<4; ++kt)
      #pragma unroll
      for (int mt=0; mt<4; ++mt) {
        int row = mt*16 + lr;
        int colb = (kt*64 + grp*16) ^ ((row&7)<<4);
        bf16x8 a = *(const bf16x8*)((const char*)&h2[row][0] + colb);
        #pragma unroll
        for (int j=0; j<4; ++j)
          acc3[mt][j] = __builtin_amdgcn_mfma_f32_16x16x32_bf16(a, b3[kt][j], acc3[mt][j], 0,0,0);
      }
    #pragma unroll
    for (int j=0; j<4; ++j) {
      float m = 0.f;   // relu folded into maxpool
      #pragma unroll
      for (int mt=0; mt<4; ++mt) {
        f32x4 t = acc3[mt][j];
        m = fmaxf(m, fmaxf(fmaxf(t[0],t[1]), fmaxf(t[2],t[3])));
      }
      m = fmaxf(m, __shfl_xor(m, 16, 64));
      m = fmaxf(m, __shfl_xor(m, 32, 64));
      if (grp == 0) out[OUT_PTS_OFF + (q0+qq)*256 + (w*4+j)*16 + lr] = m;
    }
  }
}

extern "C" void kernel_launch(void* const* d_in, const int* in_sizes, int n_in,
                              void* d_out, int out_size, void* d_ws, size_t ws_size,
                              hipStream_t stream) {
  const float* xyz      = (const float*)d_in[0];
  const float* points   = (const float*)d_in[1];
  const int*   fps_inds = (const int*)d_in[2];
  const float* w0       = (const float*)d_in[3];
  const float* w1       = (const float*)d_in[4];
  const float* w2       = (const float*)d_in[5];
  float* out = (float*)d_out;

  int*   gsidx = (int*)d_ws;
  short* px1   = (short*)d_ws + WS_PX1_SH;
  short* wsb   = (short*)d_ws + WS_WF_SH;

  hipLaunchKernelGGL(prep_weights, dim3(184), dim3(256), 0, stream, w0, w1, w2, wsb);
  hipLaunchKernelGGL(px1_kernel,   dim3(512), dim3(256), 0, stream, xyz, points, wsb, px1);
  hipLaunchKernelGGL(select_kernel,dim3(NB*NS/2), dim3(256), 0, stream, xyz, fps_inds, gsidx, out);
  hipLaunchKernelGGL(mlp_kernel,   dim3(NB*NS/QPB), dim3(256), 0, stream,
                     xyz, fps_inds, w0, wsb, px1, gsidx, out);
}

// Round 8
// 113.617 us; speedup vs baseline: 1.7295x; 1.0962x over previous
//
#include <hip/hip_runtime.h>

#define NB 8
#define NN 4096
#define NS 1024
#define NC 64
#define OUT_PTS_OFF (NB*NS*3)
#define CAP 512
#define RB 0.2f
#define QPB 8

typedef __attribute__((ext_vector_type(8))) short bf16x8;
typedef __attribute__((ext_vector_type(4))) float f32x4;

static __device__ __forceinline__ short f2bf(float f){
  unsigned u = __float_as_uint(f);
  unsigned r = (u + 0x7FFFu + ((u>>16)&1u)) >> 16;
  return (short)r;
}
static __device__ __forceinline__ float bf2f(short s){
  return __uint_as_float(((unsigned)(unsigned short)s) << 16);
}
// packed f32->bf16 RTNE: low short = cvt(a), high short = cvt(b)
static __device__ __forceinline__ unsigned cvtpk(float a, float b){
  unsigned r;
  asm("v_cvt_pk_bf16_f32 %0, %1, %2" : "=v"(r) : "v"(a), "v"(b));
  return r;
}

// ws layout (bytes) — total footprint unchanged vs proven rounds (<= 6385664):
//   ushort gsidx[8192][64]        @ 0        (1 MB)
//   float4 gxyz [8][4096]         @ 1048576  (512 KB)  cell-sorted points, .w=idx bits
//   int    cstart[8][128]         @ 1572864  (4 KB)    cells 0..124, [125]=4096
//   short  px1  [32768][64]       @ 2097152  (4 MB)
//   short  wf   [47104]           @ 6291456  (94 KB)
#define WS_PX1_SH   1048576   // in shorts
#define WS_WF_SH    3145728   // in shorts

__global__ __launch_bounds__(256) void prep_weights(
    const float* __restrict__ w0, const float* __restrict__ w1,
    const float* __restrict__ w2, short* __restrict__ ws)
{
  int e = blockIdx.x*256 + threadIdx.x;
  if (e >= 47104) return;
  float v = 0.f;
  if (e < 6144) {
    int j=e&7, l=(e>>3)&63, nt=(e>>9)&3, kt=e>>11;
    int k = kt*32 + ((l>>4)<<3) + j, n = nt*16 + (l&15);
    if (k < 64) v = w0[(3+k)*64 + n];
    else if (k < 67) v = w0[(k-64)*64 + n];
  } else if (e < 14336) {
    int e2=e-6144;
    int j=e2&7, l=(e2>>3)&63, nt=(e2>>9)&7, kt=e2>>12;
    int k = kt*32 + ((l>>4)<<3) + j, n = nt*16 + (l&15);
    v = w1[k*128 + n];
  } else {
    int e3=e-14336;
    int j=e3&7, l=(e3>>3)&63, nt=(e3>>9)&15, kt=e3>>13;
    int p = kt*32 + ((l>>4)<<3) + j;      // physical k slot (h2 storage order)
    int k = ((p&7)<<4) + (p>>3);          // logical w2 row for that slot
    int n = nt*16 + (l&15);
    v = w2[k*256 + n];
  }
  ws[e] = f2bf(v);
}

// ---- PX1[b,n,f] = ([points, xyz] @ w0_perm)[b,n,f]   (bf16, NO relu) ----
__global__ __launch_bounds__(256) void px1_kernel(
    const float* __restrict__ xyz, const float* __restrict__ points,
    const short* __restrict__ wsb, short* __restrict__ px1)
{
  const int tid = threadIdx.x;
  const int w = tid>>6, l = tid&63, lr = l&15, grp = l>>4;
  const int rowbase = blockIdx.x*64 + w*16;
  const int row = rowbase + lr;
  const float* prow = points + (size_t)row*NC;
  const float* xr   = xyz + (size_t)row*3;

  bf16x8 a0, a1, a2;
  {
    float4 u0 = *(const float4*)(prow + grp*8);
    float4 u1 = *(const float4*)(prow + grp*8 + 4);
    float4 u2 = *(const float4*)(prow + 32 + grp*8);
    float4 u3 = *(const float4*)(prow + 32 + grp*8 + 4);
    a0 = (bf16x8){f2bf(u0.x),f2bf(u0.y),f2bf(u0.z),f2bf(u0.w),f2bf(u1.x),f2bf(u1.y),f2bf(u1.z),f2bf(u1.w)};
    a1 = (bf16x8){f2bf(u2.x),f2bf(u2.y),f2bf(u2.z),f2bf(u2.w),f2bf(u3.x),f2bf(u3.y),f2bf(u3.z),f2bf(u3.w)};
    short e0=0,e1=0,e2v=0;
    if (grp==0) { e0=f2bf(xr[0]); e1=f2bf(xr[1]); e2v=f2bf(xr[2]); }
    a2 = (bf16x8){e0,e1,e2v,0,0,0,0,0};
  }
  f32x4 zero4 = {0.f,0.f,0.f,0.f};
  #pragma unroll
  for (int nt=0; nt<4; ++nt) {
    f32x4 acc = zero4;
    bf16x8 b0 = *(const bf16x8*)(wsb + (((0*4+nt)*64 + l)<<3));
    bf16x8 b1 = *(const bf16x8*)(wsb + (((1*4+nt)*64 + l)<<3));
    bf16x8 b2 = *(const bf16x8*)(wsb + (((2*4+nt)*64 + l)<<3));
    acc = __builtin_amdgcn_mfma_f32_16x16x32_bf16(a0, b0, acc, 0,0,0);
    acc = __builtin_amdgcn_mfma_f32_16x16x32_bf16(a1, b1, acc, 0,0,0);
    acc = __builtin_amdgcn_mfma_f32_16x16x32_bf16(a2, b2, acc, 0,0,0);
    #pragma unroll
    for (int i=0;i<4;++i)
      px1[(size_t)(rowbase + grp*4 + i)*64 + nt*16 + lr] = f2bf(acc[i]);
  }
}

// ---- grid build: 1 block per batch; bucket points into 5x5x5 cells ----
__global__ __launch_bounds__(256) void grid_build(
    const float* __restrict__ xyz, float4* __restrict__ gxyz, int* __restrict__ cstart)
{
  __shared__ int hist[125];
  __shared__ int base[125];
  const int b = blockIdx.x, tid = threadIdx.x;
  const float* xb = xyz + (size_t)b*NN*3;

  if (tid < 125) hist[tid] = 0;
  __syncthreads();

  float xs[16], ys[16], zs[16]; int cl[16];
  {
    const float4* xv = (const float4*)(xb + tid*48);
    #pragma unroll
    for (int g=0; g<4; ++g) {
      float4 v0 = xv[g*3], v1 = xv[g*3+1], v2 = xv[g*3+2];
      xs[g*4+0]=v0.x; xs[g*4+1]=v0.w; xs[g*4+2]=v1.z; xs[g*4+3]=v2.y;
      ys[g*4+0]=v0.y; ys[g*4+1]=v1.x; ys[g*4+2]=v1.w; ys[g*4+3]=v2.z;
      zs[g*4+0]=v0.z; zs[g*4+1]=v1.y; zs[g*4+2]=v2.x; zs[g*4+3]=v2.w;
    }
  }
  #pragma unroll
  for (int r=0; r<16; ++r) {
    int cx = min(4, (int)(xs[r]*5.0f));
    int cy = min(4, (int)(ys[r]*5.0f));
    int cz = min(4, (int)(zs[r]*5.0f));
    cl[r] = (cz*5+cy)*5+cx;
    atomicAdd(&hist[cl[r]], 1);
  }
  __syncthreads();
  if (tid == 0) {
    int acc = 0;
    for (int c=0; c<125; ++c) { base[c]=acc; cstart[b*128+c]=acc; acc+=hist[c]; }
    cstart[b*128+125] = NN;
  }
  __syncthreads();
  #pragma unroll
  for (int r=0; r<16; ++r) {
    int slot = atomicAdd(&base[cl[r]], 1);
    gxyz[b*NN + slot] = make_float4(xs[r], ys[r], zs[r], __int_as_float(tid*16+r));
  }
}

// ---- selection v2: grid-pruned ball query, exact semantics ----
__global__ __launch_bounds__(256) void select_kernel(
    const float* __restrict__ xyz, const int* __restrict__ fps_inds,
    const float4* __restrict__ gxyz, const int* __restrict__ cstart,
    unsigned short* __restrict__ gsidx, float* __restrict__ out)
{
  __shared__ unsigned int cand_d[CAP];
  __shared__ int cand_i[CAP];
  __shared__ int scell[126];
  __shared__ int seg_s[27], seg_b[27], seg_e[27];
  __shared__ int tmp64[64];
  __shared__ int cnt_sh, T_sh;

  const int q = blockIdx.x, b = q >> 10, tid = threadIdx.x;
  const float* xb = xyz + (size_t)b*NN*3;
  const int fps = fps_inds[q];
  const float qx = xb[fps*3+0], qy = xb[fps*3+1], qz = xb[fps*3+2];
  if (tid < 3) out[q*3+tid] = xb[fps*3+tid];
  if (tid < 126) scell[tid] = cstart[b*128+tid];
  if (tid == 0) cnt_sh = 0;
  __syncthreads();

  // wave-0 lanes 0..26: neighbor-cell segments + box cull + prefix
  if (tid < 32) {
    const int cx = min(4, (int)(qx*5.0f));
    const int cy = min(4, (int)(qy*5.0f));
    const int cz = min(4, (int)(qz*5.0f));
    int len = 0, s = 0;
    if (tid < 27) {
      int ncx = cx + tid%3 - 1, ncy = cy + (tid/3)%3 - 1, ncz = cz + tid/9 - 1;
      if (ncx>=0 && ncx<5 && ncy>=0 && ncy<5 && ncz>=0 && ncz<5) {
        float lox = ncx*0.2f - 1e-5f, hix = lox + 0.2f + 2e-5f;
        float loy = ncy*0.2f - 1e-5f, hiy = loy + 0.2f + 2e-5f;
        float loz = ncz*0.2f - 1e-5f, hiz = loz + 0.2f + 2e-5f;
        float dx = fmaxf(0.f, fmaxf(lox-qx, qx-hix));
        float dy = fmaxf(0.f, fmaxf(loy-qy, qy-hiy));
        float dz = fmaxf(0.f, fmaxf(loz-qz, qz-hiz));
        if (fmaf(dx,dx, fmaf(dy,dy, dz*dz)) <= 0.0402f) {
          int c = (ncz*5+ncy)*5+ncx;
          s = scell[c]; len = scell[c+1] - s;
        }
      }
    }
    int incl = len;
    #pragma unroll
    for (int off=1; off<32; off<<=1) {
      int v = __shfl_up(incl, off, 32);
      if (tid >= off) incl += v;
    }
    if (tid < 27) { seg_s[tid]=s; seg_b[tid]=incl-len; seg_e[tid]=incl; }
    if (tid == 31) T_sh = incl;
  }
  __syncthreads();

  const int T = T_sh;
  const float4* gb = gxyz + b*NN;
  {
    int k = 0;
    for (int t = tid; t < T; t += 256) {
      while (t >= seg_e[k]) ++k;          // k only advances (t increasing)
      float4 p = gb[seg_s[k] + (t - seg_b[k])];
      float fx = qx-p.x, fy = qy-p.y, fz = qz-p.z;
      float ff = fmaf(fx,fx, fmaf(fy,fy, fz*fz));
      if (ff < 0.0402f) {
        // exact reference chain (bit-identical to brute force)
        float dx=__fsub_rn(qx,p.x), dy=__fsub_rn(qy,p.y), dz=__fsub_rn(qz,p.z);
        float d2=__fadd_rn(__fadd_rn(__fmul_rn(dx,dx),__fmul_rn(dy,dy)),__fmul_rn(dz,dz));
        float d = __fsqrt_rn(d2);
        if (d < RB) {
          int pos = atomicAdd(&cnt_sh, 1);
          if (pos < CAP) { cand_d[pos] = __float_as_uint(d); cand_i[pos] = __float_as_int(p.w); }
        }
      }
    }
  }
  __syncthreads();
  int cnt = cnt_sh; if (cnt > CAP) cnt = CAP;

  if (cnt > 64) {
    // 64 smallest by (dist, idx)
    for (int j=tid; j<cnt; j+=256) {
      unsigned dj = cand_d[j]; int ij = cand_i[j]; int rk = 0;
      for (int i=0; i<cnt; ++i) {
        unsigned di = cand_d[i];
        rk += (int)((di<dj) | ((di==dj) & (cand_i[i]<ij)));
      }
      if (rk < 64) tmp64[rk] = ij;
    }
    __syncthreads();
    if (tid < 64) {
      int v = tmp64[tid]; int p = 0;
      #pragma unroll
      for (int u=0; u<64; ++u) p += (tmp64[u] < v);
      gsidx[q*64 + p] = (unsigned short)v;
    }
  } else {
    // all candidates valid: sort by idx, pad with min idx
    if (tid < cnt) {
      int v = cand_i[tid]; int p = 0;
      for (int u=0; u<cnt; ++u) p += (cand_i[u] < v);
      tmp64[p] = v;
    }
    __syncthreads();
    if (tid < 64) gsidx[q*64 + tid] = (unsigned short)tmp64[tid < cnt ? tid : 0];
  }
}

// ---- MLP: persistent QPB queries/block; wf2 in regs, wf1 in LDS ----
// launch_bounds (256,2): DO NOT raise — (256,4) spilled b3 (R6: VGPR=64, 139us).
__global__ __launch_bounds__(256,2) void mlp_kernel(
    const float* __restrict__ xyz, const int* __restrict__ fps_inds,
    const float* __restrict__ w0, const short* __restrict__ wsb,
    const short* __restrict__ px1, const unsigned short* __restrict__ gsidx,
    float* __restrict__ out)
{
  __shared__ __align__(16) short w1s[16*64*8];   // 16384 B, loaded once
  __shared__ __align__(16) short h2[64][136];    // 17408 B, single-buffered
  __shared__ float q1s[QPB][64];
  __shared__ int sidx[QPB][64];

  const int tid = threadIdx.x;
  const int w = tid>>6, l = tid&63, lr = l&15, grp = l>>4;
  const int q0 = blockIdx.x*QPB;
  const int b = q0 >> 10;
  const float* xb = xyz + (size_t)b*NN*3;

  bf16x8 b3[4][4];
  #pragma unroll
  for (int kt=0; kt<4; ++kt)
    #pragma unroll
    for (int j=0; j<4; ++j)
      b3[kt][j] = *(const bf16x8*)(wsb + 14336 + (((kt*16 + w*4 + j)*64 + l)<<3));

  #pragma unroll
  for (int e = 0; e < 4; ++e) {
    int s = tid + e*256;
    *(bf16x8*)&w1s[s*8] = *(const bf16x8*)(wsb + 6144 + s*8);
  }
  for (int e = tid; e < QPB*64; e += 256) {
    int qq = e>>6, t = e&63;
    int fp = fps_inds[q0+qq];
    sidx[qq][t] = (int)gsidx[(q0+qq)*64 + t];
    q1s[qq][t] = xb[fp*3]*w0[t] + xb[fp*3+1]*w0[64+t] + xb[fp*3+2]*w0[128+t];
  }
  if (tid < QPB*3) {
    int qq = tid/3, c = tid - qq*3;
    int fp = fps_inds[q0+qq];
    out[(q0+qq)*3 + c] = xb[fp*3+c];
  }
  __syncthreads();

  const short* px1b = px1 + (size_t)b*NN*64;
  const int myrow = w*16 + lr;

  bf16x8 v0, v1;
  {
    int idx = sidx[0][myrow];
    v0 = *(const bf16x8*)(px1b + idx*64 + grp*8);
    v1 = *(const bf16x8*)(px1b + idx*64 + 32 + grp*8);
  }

  f32x4 zero4 = {0.f,0.f,0.f,0.f};

  for (int qq = 0; qq < QPB; ++qq) {
    if (qq) __syncthreads();

    bf16x8 a20, a21;
    {
      union { unsigned u[4]; bf16x8 v; } ua, ub;
      #pragma unroll
      for (int jp=0; jp<4; ++jp) {
        float x0 = fmaxf(bf2f(v0[2*jp  ]) - q1s[qq][grp*8+2*jp  ], 0.f);
        float x1 = fmaxf(bf2f(v0[2*jp+1]) - q1s[qq][grp*8+2*jp+1], 0.f);
        ua.u[jp] = cvtpk(x0, x1);
        float y0 = fmaxf(bf2f(v1[2*jp  ]) - q1s[qq][32+grp*8+2*jp  ], 0.f);
        float y1 = fmaxf(bf2f(v1[2*jp+1]) - q1s[qq][32+grp*8+2*jp+1], 0.f);
        ub.u[jp] = cvtpk(y0, y1);
      }
      a20 = ua.v; a21 = ub.v;
    }
    if (qq+1 < QPB) {
      int idx = sidx[qq+1][myrow];
      v0 = *(const bf16x8*)(px1b + idx*64 + grp*8);
      v1 = *(const bf16x8*)(px1b + idx*64 + 32 + grp*8);
    }

    #pragma unroll
    for (int ntp=0; ntp<4; ++ntp) {
      f32x4 accA = zero4, accB = zero4;
      bf16x8 bA0 = *(const bf16x8*)&w1s[((0*8 + 2*ntp  )*64 + l)*8];
      bf16x8 bA1 = *(const bf16x8*)&w1s[((1*8 + 2*ntp  )*64 + l)*8];
      bf16x8 bB0 = *(const bf16x8*)&w1s[((0*8 + 2*ntp+1)*64 + l)*8];
      bf16x8 bB1 = *(const bf16x8*)&w1s[((1*8 + 2*ntp+1)*64 + l)*8];
      accA = __builtin_amdgcn_mfma_f32_16x16x32_bf16(a20, bA0, accA, 0,0,0);
      accA = __builtin_amdgcn_mfma_f32_16x16x32_bf16(a21, bA1, accA, 0,0,0);
      accB = __builtin_amdgcn_mfma_f32_16x16x32_bf16(a20, bB0, accB, 0,0,0);
      accB = __builtin_amdgcn_mfma_f32_16x16x32_bf16(a21, bB1, accB, 0,0,0);
      #pragma unroll
      for (int i=0; i<4; ++i) {
        int row = w*16 + grp*4 + i;
        unsigned u = cvtpk(fmaxf(accA[i],0.f), fmaxf(accB[i],0.f));
        int colb = (lr*16 + ntp*4) ^ ((row&7)<<4);
        *(unsigned*)((char*)&h2[row][0] + colb) = u;
      }
    }
    __syncthreads();

    f32x4 acc3[4][4];
    #pragma unroll
    for (int mt=0; mt<4; ++mt)
      #pragma unroll
      for (int j=0; j<4; ++j) acc3[mt][j] = zero4;
    #pragma unroll
    for (int kt=0; kt<4; ++kt)
      #pragma unroll
      for (int mt=0; mt<4; ++mt) {
        int row = mt*16 + lr;
        int colb = (kt*64 + grp*16) ^ ((row&7)<<4);
        bf16x8 a = *(const bf16x8*)((const char*)&h2[row][0] + colb);
        #pragma unroll
        for (int j=0; j<4; ++j)
          acc3[mt][j] = __builtin_amdgcn_mfma_f32_16x16x32_bf16(a, b3[kt][j], acc3[mt][j], 0,0,0);
      }
    #pragma unroll
    for (int j=0; j<4; ++j) {
      float m = 0.f;
      #pragma unroll
      for (int mt=0; mt<4; ++mt) {
        f32x4 t = acc3[mt][j];
        m = fmaxf(m, fmaxf(fmaxf(t[0],t[1]), fmaxf(t[2],t[3])));
      }
      m = fmaxf(m, __shfl_xor(m, 16, 64));
      m = fmaxf(m, __shfl_xor(m, 32, 64));
      if (grp == 0) out[OUT_PTS_OFF + (q0+qq)*256 + (w*4+j)*16 + lr] = m;
    }
  }
}

extern "C" void kernel_launch(void* const* d_in, const int* in_sizes, int n_in,
                              void* d_out, int out_size, void* d_ws, size_t ws_size,
                              hipStream_t stream) {
  const float* xyz      = (const float*)d_in[0];
  const float* points   = (const float*)d_in[1];
  const int*   fps_inds = (const int*)d_in[2];
  const float* w0       = (const float*)d_in[3];
  const float* w1       = (const float*)d_in[4];
  const float* w2       = (const float*)d_in[5];
  float* out = (float*)d_out;

  unsigned short* gsidx = (unsigned short*)d_ws;
  float4* gxyz  = (float4*)((char*)d_ws + 1048576);
  int*    cstart= (int*)((char*)d_ws + 1572864);
  short*  px1   = (short*)d_ws + WS_PX1_SH;
  short*  wsb   = (short*)d_ws + WS_WF_SH;

  hipLaunchKernelGGL(prep_weights, dim3(184), dim3(256), 0, stream, w0, w1, w2, wsb);
  hipLaunchKernelGGL(grid_build,   dim3(NB),  dim3(256), 0, stream, xyz, gxyz, cstart);
  hipLaunchKernelGGL(px1_kernel,   dim3(512), dim3(256), 0, stream, xyz, points, wsb, px1);
  hipLaunchKernelGGL(select_kernel,dim3(NB*NS), dim3(256), 0, stream,
                     xyz, fps_inds, gxyz, cstart, gsidx, out);
  hipLaunchKernelGGL(mlp_kernel,   dim3(NB*NS/QPB), dim3(256), 0, stream,
                     xyz, fps_inds, w0, wsb, px1, gsidx, out);
}

// Round 9
// 108.120 us; speedup vs baseline: 1.8175x; 1.0508x over previous
//
#include <hip/hip_runtime.h>

#define NB 8
#define NN 4096
#define NS 1024
#define NC 64
#define OUT_PTS_OFF (NB*NS*3)
#define CAP 512
#define RB 0.2f
#define QPB 8

typedef __attribute__((ext_vector_type(8))) short bf16x8;
typedef __attribute__((ext_vector_type(4))) float f32x4;

static __device__ __forceinline__ short f2bf(float f){
  unsigned u = __float_as_uint(f);
  unsigned r = (u + 0x7FFFu + ((u>>16)&1u)) >> 16;
  return (short)r;
}
static __device__ __forceinline__ float bf2f(short s){
  return __uint_as_float(((unsigned)(unsigned short)s) << 16);
}
// packed f32->bf16 RTNE: low short = cvt(a), high short = cvt(b)
static __device__ __forceinline__ unsigned cvtpk(float a, float b){
  unsigned r;
  asm("v_cvt_pk_bf16_f32 %0, %1, %2" : "=v"(r) : "v"(a), "v"(b));
  return r;
}

// ws layout (bytes):
//   ushort gsidx[8192][64]        @ 0        (1 MB)
//   float4 gxyz [8][4096]         @ 1048576  (512 KB)  cell-sorted points, .w=idx bits
//   int    cstart[8][128]         @ 1572864  (4 KB)
//   short  px1  [32768][64]       @ 2097152  (4 MB)
//   short  wf   [47104]           @ 6291456  (94 KB)
#define WS_PX1_SH   1048576   // in shorts
#define WS_WF_SH    3145728   // in shorts

__global__ __launch_bounds__(256) void prep_weights(
    const float* __restrict__ w0, const float* __restrict__ w1,
    const float* __restrict__ w2, short* __restrict__ ws)
{
  int e = blockIdx.x*256 + threadIdx.x;
  if (e >= 47104) return;
  float v = 0.f;
  if (e < 6144) {
    int j=e&7, l=(e>>3)&63, nt=(e>>9)&3, kt=e>>11;
    int k = kt*32 + ((l>>4)<<3) + j, n = nt*16 + (l&15);
    if (k < 64) v = w0[(3+k)*64 + n];
    else if (k < 67) v = w0[(k-64)*64 + n];
  } else if (e < 14336) {
    int e2=e-6144;
    int j=e2&7, l=(e2>>3)&63, nt=(e2>>9)&7, kt=e2>>12;
    int k = kt*32 + ((l>>4)<<3) + j, n = nt*16 + (l&15);
    v = w1[k*128 + n];
  } else {
    // wf2 k-relabel matches fragment-ordered h2f: storage coord (kt,grp,j)
    // holds logical w2 row (kt*2+(j&1))*16 + grp*4 + (j>>1)
    int e3=e-14336;
    int j=e3&7, l=(e3>>3)&63, nt=(e3>>9)&15, kt=e3>>13;
    int k = (kt*2 + (j&1))*16 + ((l>>4)<<2) + (j>>1);
    v = w2[k*256 + nt*16 + (l&15)];
  }
  ws[e] = f2bf(v);
}

// ---- PX1[b,n,f] = ([points, xyz] @ w0_perm)[b,n,f]   (bf16, NO relu) ----
__global__ __launch_bounds__(256) void px1_kernel(
    const float* __restrict__ xyz, const float* __restrict__ points,
    const short* __restrict__ wsb, short* __restrict__ px1)
{
  const int tid = threadIdx.x;
  const int w = tid>>6, l = tid&63, lr = l&15, grp = l>>4;
  const int rowbase = blockIdx.x*64 + w*16;
  const int row = rowbase + lr;
  const float* prow = points + (size_t)row*NC;
  const float* xr   = xyz + (size_t)row*3;

  bf16x8 a0, a1, a2;
  {
    float4 u0 = *(const float4*)(prow + grp*8);
    float4 u1 = *(const float4*)(prow + grp*8 + 4);
    float4 u2 = *(const float4*)(prow + 32 + grp*8);
    float4 u3 = *(const float4*)(prow + 32 + grp*8 + 4);
    a0 = (bf16x8){f2bf(u0.x),f2bf(u0.y),f2bf(u0.z),f2bf(u0.w),f2bf(u1.x),f2bf(u1.y),f2bf(u1.z),f2bf(u1.w)};
    a1 = (bf16x8){f2bf(u2.x),f2bf(u2.y),f2bf(u2.z),f2bf(u2.w),f2bf(u3.x),f2bf(u3.y),f2bf(u3.z),f2bf(u3.w)};
    short e0=0,e1=0,e2v=0;
    if (grp==0) { e0=f2bf(xr[0]); e1=f2bf(xr[1]); e2v=f2bf(xr[2]); }
    a2 = (bf16x8){e0,e1,e2v,0,0,0,0,0};
  }
  f32x4 zero4 = {0.f,0.f,0.f,0.f};
  #pragma unroll
  for (int nt=0; nt<4; ++nt) {
    f32x4 acc = zero4;
    bf16x8 b0 = *(const bf16x8*)(wsb + (((0*4+nt)*64 + l)<<3));
    bf16x8 b1 = *(const bf16x8*)(wsb + (((1*4+nt)*64 + l)<<3));
    bf16x8 b2 = *(const bf16x8*)(wsb + (((2*4+nt)*64 + l)<<3));
    acc = __builtin_amdgcn_mfma_f32_16x16x32_bf16(a0, b0, acc, 0,0,0);
    acc = __builtin_amdgcn_mfma_f32_16x16x32_bf16(a1, b1, acc, 0,0,0);
    acc = __builtin_amdgcn_mfma_f32_16x16x32_bf16(a2, b2, acc, 0,0,0);
    #pragma unroll
    for (int i=0;i<4;++i)
      px1[(size_t)(rowbase + grp*4 + i)*64 + nt*16 + lr] = f2bf(acc[i]);
  }
}

// ---- grid build: 1 block per batch; bucket points into 5x5x5 cells ----
__global__ __launch_bounds__(256) void grid_build(
    const float* __restrict__ xyz, float4* __restrict__ gxyz, int* __restrict__ cstart)
{
  __shared__ int hist[125];
  __shared__ int base[125];
  const int b = blockIdx.x, tid = threadIdx.x;
  const float* xb = xyz + (size_t)b*NN*3;

  if (tid < 125) hist[tid] = 0;
  __syncthreads();

  float xs[16], ys[16], zs[16]; int cl[16];
  {
    const float4* xv = (const float4*)(xb + tid*48);
    #pragma unroll
    for (int g=0; g<4; ++g) {
      float4 v0 = xv[g*3], v1 = xv[g*3+1], v2 = xv[g*3+2];
      xs[g*4+0]=v0.x; xs[g*4+1]=v0.w; xs[g*4+2]=v1.z; xs[g*4+3]=v2.y;
      ys[g*4+0]=v0.y; ys[g*4+1]=v1.x; ys[g*4+2]=v1.w; ys[g*4+3]=v2.z;
      zs[g*4+0]=v0.z; zs[g*4+1]=v1.y; zs[g*4+2]=v2.x; zs[g*4+3]=v2.w;
    }
  }
  #pragma unroll
  for (int r=0; r<16; ++r) {
    int cx = min(4, (int)(xs[r]*5.0f));
    int cy = min(4, (int)(ys[r]*5.0f));
    int cz = min(4, (int)(zs[r]*5.0f));
    cl[r] = (cz*5+cy)*5+cx;
    atomicAdd(&hist[cl[r]], 1);
  }
  __syncthreads();
  if (tid == 0) {
    int acc = 0;
    for (int c=0; c<125; ++c) { base[c]=acc; cstart[b*128+c]=acc; acc+=hist[c]; }
    cstart[b*128+125] = NN;
  }
  __syncthreads();
  #pragma unroll
  for (int r=0; r<16; ++r) {
    int slot = atomicAdd(&base[cl[r]], 1);
    gxyz[b*NN + slot] = make_float4(xs[r], ys[r], zs[r], __int_as_float(tid*16+r));
  }
}

// ---- selection v2: grid-pruned ball query, exact semantics ----
__global__ __launch_bounds__(256) void select_kernel(
    const float* __restrict__ xyz, const int* __restrict__ fps_inds,
    const float4* __restrict__ gxyz, const int* __restrict__ cstart,
    unsigned short* __restrict__ gsidx, float* __restrict__ out)
{
  __shared__ unsigned int cand_d[CAP];
  __shared__ int cand_i[CAP];
  __shared__ int scell[126];
  __shared__ int seg_s[27], seg_b[27], seg_e[27];
  __shared__ int tmp64[64];
  __shared__ int cnt_sh, T_sh;

  const int q = blockIdx.x, b = q >> 10, tid = threadIdx.x;
  const float* xb = xyz + (size_t)b*NN*3;
  const int fps = fps_inds[q];
  const float qx = xb[fps*3+0], qy = xb[fps*3+1], qz = xb[fps*3+2];
  if (tid < 3) out[q*3+tid] = xb[fps*3+tid];
  if (tid < 126) scell[tid] = cstart[b*128+tid];
  if (tid == 0) cnt_sh = 0;
  __syncthreads();

  if (tid < 32) {
    const int cx = min(4, (int)(qx*5.0f));
    const int cy = min(4, (int)(qy*5.0f));
    const int cz = min(4, (int)(qz*5.0f));
    int len = 0, s = 0;
    if (tid < 27) {
      int ncx = cx + tid%3 - 1, ncy = cy + (tid/3)%3 - 1, ncz = cz + tid/9 - 1;
      if (ncx>=0 && ncx<5 && ncy>=0 && ncy<5 && ncz>=0 && ncz<5) {
        float lox = ncx*0.2f - 1e-5f, hix = lox + 0.2f + 2e-5f;
        float loy = ncy*0.2f - 1e-5f, hiy = loy + 0.2f + 2e-5f;
        float loz = ncz*0.2f - 1e-5f, hiz = loz + 0.2f + 2e-5f;
        float dx = fmaxf(0.f, fmaxf(lox-qx, qx-hix));
        float dy = fmaxf(0.f, fmaxf(loy-qy, qy-hiy));
        float dz = fmaxf(0.f, fmaxf(loz-qz, qz-hiz));
        if (fmaf(dx,dx, fmaf(dy,dy, dz*dz)) <= 0.0402f) {
          int c = (ncz*5+ncy)*5+ncx;
          s = scell[c]; len = scell[c+1] - s;
        }
      }
    }
    int incl = len;
    #pragma unroll
    for (int off=1; off<32; off<<=1) {
      int v = __shfl_up(incl, off, 32);
      if (tid >= off) incl += v;
    }
    if (tid < 27) { seg_s[tid]=s; seg_b[tid]=incl-len; seg_e[tid]=incl; }
    if (tid == 31) T_sh = incl;
  }
  __syncthreads();

  const int T = T_sh;
  const float4* gb = gxyz + b*NN;
  {
    int k = 0;
    for (int t = tid; t < T; t += 256) {
      while (t >= seg_e[k]) ++k;
      float4 p = gb[seg_s[k] + (t - seg_b[k])];
      float fx = qx-p.x, fy = qy-p.y, fz = qz-p.z;
      float ff = fmaf(fx,fx, fmaf(fy,fy, fz*fz));
      if (ff < 0.0402f) {
        float dx=__fsub_rn(qx,p.x), dy=__fsub_rn(qy,p.y), dz=__fsub_rn(qz,p.z);
        float d2=__fadd_rn(__fadd_rn(__fmul_rn(dx,dx),__fmul_rn(dy,dy)),__fmul_rn(dz,dz));
        float d = __fsqrt_rn(d2);
        if (d < RB) {
          int pos = atomicAdd(&cnt_sh, 1);
          if (pos < CAP) { cand_d[pos] = __float_as_uint(d); cand_i[pos] = __float_as_int(p.w); }
        }
      }
    }
  }
  __syncthreads();
  int cnt = cnt_sh; if (cnt > CAP) cnt = CAP;

  if (cnt > 64) {
    for (int j=tid; j<cnt; j+=256) {
      unsigned dj = cand_d[j]; int ij = cand_i[j]; int rk = 0;
      for (int i=0; i<cnt; ++i) {
        unsigned di = cand_d[i];
        rk += (int)((di<dj) | ((di==dj) & (cand_i[i]<ij)));
      }
      if (rk < 64) tmp64[rk] = ij;
    }
    __syncthreads();
    if (tid < 64) {
      int v = tmp64[tid]; int p = 0;
      #pragma unroll
      for (int u=0; u<64; ++u) p += (tmp64[u] < v);
      gsidx[q*64 + p] = (unsigned short)v;
    }
  } else {
    if (tid < cnt) {
      int v = cand_i[tid]; int p = 0;
      for (int u=0; u<cnt; ++u) p += (cand_i[u] < v);
      tmp64[p] = v;
    }
    __syncthreads();
    if (tid < 64) gsidx[q*64 + tid] = (unsigned short)tmp64[tid < cnt ? tid : 0];
  }
}

// ---- MLP: persistent QPB queries/block; wf2 in regs, wf1 in LDS ----
// h2f is FRAGMENT-ORDERED: 16B slot [(mt*4+kt)*64 + lane] = lane's layer-3
// A-fragment (8 bf16, j=0..7). Channel relabel: n=nt*16+lr2 <-> (kt=nt>>1,
// grp=lr2>>2, j=(lr2&3)*2+(nt&1)); wf2 rows permuted to match (prep_weights).
// Byte bits 4-5 XORed with u=(slot>>4)&3 on BOTH sides: write lands 2 lanes/bank
// (free), read remains contiguous-per-128B (conflict-free).
// launch_bounds (256,2): DO NOT raise — (256,4) spilled b3 (R6: VGPR=64, 139us).
__global__ __launch_bounds__(256,2) void mlp_kernel(
    const float* __restrict__ xyz, const int* __restrict__ fps_inds,
    const float* __restrict__ w0, const short* __restrict__ wsb,
    const short* __restrict__ px1, const unsigned short* __restrict__ gsidx,
    float* __restrict__ out)
{
  __shared__ __align__(16) short w1s[16*64*8];   // 16384 B, loaded once
  __shared__ __align__(16) short h2f[8192];      // 16384 B, fragment-ordered
  __shared__ float q1s[QPB][64];
  __shared__ int sidx[QPB][64];

  const int tid = threadIdx.x;
  const int w = tid>>6, l = tid&63, lr = l&15, grp = l>>4;
  const int q0 = blockIdx.x*QPB;
  const int b = q0 >> 10;
  const float* xb = xyz + (size_t)b*NN*3;

  bf16x8 b3[4][4];
  #pragma unroll
  for (int kt=0; kt<4; ++kt)
    #pragma unroll
    for (int j=0; j<4; ++j)
      b3[kt][j] = *(const bf16x8*)(wsb + 14336 + (((kt*16 + w*4 + j)*64 + l)<<3));

  #pragma unroll
  for (int e = 0; e < 4; ++e) {
    int s = tid + e*256;
    *(bf16x8*)&w1s[s*8] = *(const bf16x8*)(wsb + 6144 + s*8);
  }
  for (int e = tid; e < QPB*64; e += 256) {
    int qq = e>>6, t = e&63;
    int fp = fps_inds[q0+qq];
    sidx[qq][t] = (int)gsidx[(q0+qq)*64 + t];
    q1s[qq][t] = xb[fp*3]*w0[t] + xb[fp*3+1]*w0[64+t] + xb[fp*3+2]*w0[128+t];
  }
  if (tid < QPB*3) {
    int qq = tid/3, c = tid - qq*3;
    int fp = fps_inds[q0+qq];
    out[(q0+qq)*3 + c] = xb[fp*3+c];
  }
  __syncthreads();

  const short* px1b = px1 + (size_t)b*NN*64;
  const int myrow = w*16 + lr;

  bf16x8 v0, v1;
  {
    int idx = sidx[0][myrow];
    v0 = *(const bf16x8*)(px1b + idx*64 + grp*8);
    v1 = *(const bf16x8*)(px1b + idx*64 + 32 + grp*8);
  }

  f32x4 zero4 = {0.f,0.f,0.f,0.f};
  const int uu4 = (lr>>2) << 4;     // write-side XOR (byte bits 4-5)
  const int gg4 = grp << 4;         // read-side XOR  (byte bits 4-5)

  for (int qq = 0; qq < QPB; ++qq) {
    if (qq) __syncthreads();

    bf16x8 a20, a21;
    {
      union { unsigned u[4]; bf16x8 v; } ua, ub;
      #pragma unroll
      for (int jp=0; jp<4; ++jp) {
        float x0 = fmaxf(bf2f(v0[2*jp  ]) - q1s[qq][grp*8+2*jp  ], 0.f);
        float x1 = fmaxf(bf2f(v0[2*jp+1]) - q1s[qq][grp*8+2*jp+1], 0.f);
        ua.u[jp] = cvtpk(x0, x1);
        float y0 = fmaxf(bf2f(v1[2*jp  ]) - q1s[qq][32+grp*8+2*jp  ], 0.f);
        float y1 = fmaxf(bf2f(v1[2*jp+1]) - q1s[qq][32+grp*8+2*jp+1], 0.f);
        ub.u[jp] = cvtpk(y0, y1);
      }
      a20 = ua.v; a21 = ub.v;
    }
    if (qq+1 < QPB) {
      int idx = sidx[qq+1][myrow];
      v0 = *(const bf16x8*)(px1b + idx*64 + grp*8);
      v1 = *(const bf16x8*)(px1b + idx*64 + 32 + grp*8);
    }

    // layer 2: B from LDS; packed b32 stores into fragment-ordered h2f
    #pragma unroll
    for (int ntp=0; ntp<4; ++ntp) {
      f32x4 accA = zero4, accB = zero4;
      bf16x8 bA0 = *(const bf16x8*)&w1s[((0*8 + 2*ntp  )*64 + l)*8];
      bf16x8 bA1 = *(const bf16x8*)&w1s[((1*8 + 2*ntp  )*64 + l)*8];
      bf16x8 bB0 = *(const bf16x8*)&w1s[((0*8 + 2*ntp+1)*64 + l)*8];
      bf16x8 bB1 = *(const bf16x8*)&w1s[((1*8 + 2*ntp+1)*64 + l)*8];
      accA = __builtin_amdgcn_mfma_f32_16x16x32_bf16(a20, bA0, accA, 0,0,0);
      accA = __builtin_amdgcn_mfma_f32_16x16x32_bf16(a21, bA1, accA, 0,0,0);
      accB = __builtin_amdgcn_mfma_f32_16x16x32_bf16(a20, bB0, accB, 0,0,0);
      accB = __builtin_amdgcn_mfma_f32_16x16x32_bf16(a21, bB1, accB, 0,0,0);
      #pragma unroll
      for (int i=0; i<4; ++i) {
        // slot (w*4+ntp)*64 + (lr>>2)*16 + grp*4 + i, word (lr&3)
        unsigned pv = cvtpk(fmaxf(accA[i],0.f), fmaxf(accB[i],0.f));
        int byteoff = ((((w*4+ntp)*64 + (lr>>2)*16 + grp*4 + i)<<4) + ((lr&3)<<2)) ^ uu4;
        *(unsigned*)((char*)h2f + byteoff) = pv;
      }
    }
    __syncthreads();

    // layer 3: contiguous fragment reads; B from regs
    f32x4 acc3[4][4];
    #pragma unroll
    for (int mt=0; mt<4; ++mt)
      #pragma unroll
      for (int j=0; j<4; ++j) acc3[mt][j] = zero4;
    #pragma unroll
    for (int kt=0; kt<4; ++kt)
      #pragma unroll
      for (int mt=0; mt<4; ++mt) {
        int byteoff = ((((mt*4+kt)*64 + l)<<4)) ^ gg4;
        bf16x8 a = *(const bf16x8*)((const char*)h2f + byteoff);
        #pragma unroll
        for (int j=0; j<4; ++j)
          acc3[mt][j] = __builtin_amdgcn_mfma_f32_16x16x32_bf16(a, b3[kt][j], acc3[mt][j], 0,0,0);
      }
    #pragma unroll
    for (int j=0; j<4; ++j) {
      float m = 0.f;
      #pragma unroll
      for (int mt=0; mt<4; ++mt) {
        f32x4 t = acc3[mt][j];
        m = fmaxf(m, fmaxf(fmaxf(t[0],t[1]), fmaxf(t[2],t[3])));
      }
      m = fmaxf(m, __shfl_xor(m, 16, 64));
      m = fmaxf(m, __shfl_xor(m, 32, 64));
      if (grp == 0) out[OUT_PTS_OFF + (q0+qq)*256 + (w*4+j)*16 + lr] = m;
    }
  }
}

extern "C" void kernel_launch(void* const* d_in, const int* in_sizes, int n_in,
                              void* d_out, int out_size, void* d_ws, size_t ws_size,
                              hipStream_t stream) {
  const float* xyz      = (const float*)d_in[0];
  const float* points   = (const float*)d_in[1];
  const int*   fps_inds = (const int*)d_in[2];
  const float* w0       = (const float*)d_in[3];
  const float* w1       = (const float*)d_in[4];
  const float* w2       = (const float*)d_in[5];
  float* out = (float*)d_out;

  unsigned short* gsidx = (unsigned short*)d_ws;
  float4* gxyz  = (float4*)((char*)d_ws + 1048576);
  int*    cstart= (int*)((char*)d_ws + 1572864);
  short*  px1   = (short*)d_ws + WS_PX1_SH;
  short*  wsb   = (short*)d_ws + WS_WF_SH;

  hipLaunchKernelGGL(prep_weights, dim3(184), dim3(256), 0, stream, w0, w1, w2, wsb);
  hipLaunchKernelGGL(grid_build,   dim3(NB),  dim3(256), 0, stream, xyz, gxyz, cstart);
  hipLaunchKernelGGL(px1_kernel,   dim3(512), dim3(256), 0, stream, xyz, points, wsb, px1);
  hipLaunchKernelGGL(select_kernel,dim3(NB*NS), dim3(256), 0, stream,
                     xyz, fps_inds, gxyz, cstart, gsidx, out);
  hipLaunchKernelGGL(mlp_kernel,   dim3(NB*NS/QPB), dim3(256), 0, stream,
                     xyz, fps_inds, w0, wsb, px1, gsidx, out);
}